// Round 1
// baseline (2077.665 us; speedup 1.0000x reference)
//
#include <hip/hip_runtime.h>
#include <cstddef>

#define NREL 4
#define HD 64
#define FD 128

static inline int idiv_up(int a, int b) { return (a + b - 1) / b; }

// ---------------- CSR build (dst-sorted adjacency, per relation) ----------------

__global__ void hist_kernel(const int* __restrict__ dst, int* __restrict__ deg, int E, int N) {
    int k = blockIdx.y;
    const int* dk = dst + (size_t)k * E;
    int* degk = deg + (size_t)k * N;
    for (int e = blockIdx.x * blockDim.x + threadIdx.x; e < E; e += gridDim.x * blockDim.x)
        atomicAdd(&degk[dk[e]], 1);
}

// one block (1024 threads) per relation: chunked exclusive scan of deg -> rowptr, cursor
__global__ void scan_kernel(const int* __restrict__ deg, int* __restrict__ rowptr,
                            int* __restrict__ cursor, int N, int E) {
    int k = blockIdx.x;
    __shared__ int sdata[1024];
    __shared__ int scarry;
    int tid = threadIdx.x;
    if (tid == 0) scarry = 0;
    __syncthreads();
    for (int base = 0; base < N; base += 1024) {
        int i = base + tid;
        int v = (i < N) ? deg[(size_t)k * N + i] : 0;
        sdata[tid] = v;
        __syncthreads();
        #pragma unroll
        for (int off = 1; off < 1024; off <<= 1) {
            int t = (tid >= off) ? sdata[tid - off] : 0;
            __syncthreads();
            sdata[tid] += t;
            __syncthreads();
        }
        int incl = sdata[tid];
        int carry = scarry;
        if (i < N) {
            int excl = carry + incl - v;
            rowptr[(size_t)k * (N + 1) + i] = excl;
            cursor[(size_t)k * N + i] = excl;
        }
        __syncthreads();
        if (tid == 1023) scarry = carry + incl;
        __syncthreads();
    }
    if (tid == 0) rowptr[(size_t)k * (N + 1) + N] = E;
}

__global__ void fill_kernel(const int* __restrict__ src, const int* __restrict__ dst,
                            const float* __restrict__ ew, int* __restrict__ cursor,
                            int* __restrict__ ssrc, float* __restrict__ sw, int E, int N) {
    int k = blockIdx.y;
    const int* sk = src + (size_t)k * E;
    const int* dk = dst + (size_t)k * E;
    const float* wk = ew + (size_t)k * E;
    int* ck = cursor + (size_t)k * N;
    int* ok = ssrc + (size_t)k * E;
    float* owk = sw + (size_t)k * E;
    for (int e = blockIdx.x * blockDim.x + threadIdx.x; e < E; e += gridDim.x * blockDim.x) {
        int d = dk[e];
        int pos = atomicAdd(&ck[d], 1);
        ok[pos] = sk[e];
        owk[pos] = wk[e];
    }
}

// ---------------- Dense GEMM: Y[k] = X_{k%2} @ W_k  (K x 64), W in LDS ----------------

template <int K>
__global__ void gemm_kernel(const float* __restrict__ X0, const float* __restrict__ X1,
                            const float* __restrict__ Wbase, float* __restrict__ Ybase, int N) {
    __shared__ float sW[K * HD];
    int k = blockIdx.y;
    const float* X = (k & 1) ? X1 : X0;
    const float* W = Wbase + (size_t)k * K * HD;
    float* Y = Ybase + (size_t)k * N * HD;
    int tid = threadIdx.x;
    for (int i = tid * 4; i < K * HD; i += 256 * 4)
        *reinterpret_cast<float4*>(&sW[i]) = *reinterpret_cast<const float4*>(&W[i]);
    __syncthreads();
    int row = blockIdx.x * 16 + (tid >> 4);
    int col = (tid & 15) * 4;
    if (row >= N) return;
    const float* xr = X + (size_t)row * K;
    float4 acc = {0.f, 0.f, 0.f, 0.f};
    #pragma unroll 8
    for (int kk = 0; kk < K; kk += 4) {
        float4 xv = *reinterpret_cast<const float4*>(xr + kk);
        float4 w0 = *reinterpret_cast<const float4*>(&sW[(kk + 0) * HD + col]);
        float4 w1 = *reinterpret_cast<const float4*>(&sW[(kk + 1) * HD + col]);
        float4 w2 = *reinterpret_cast<const float4*>(&sW[(kk + 2) * HD + col]);
        float4 w3 = *reinterpret_cast<const float4*>(&sW[(kk + 3) * HD + col]);
        acc.x += xv.x * w0.x + xv.y * w1.x + xv.z * w2.x + xv.w * w3.x;
        acc.y += xv.x * w0.y + xv.y * w1.y + xv.z * w2.y + xv.w * w3.y;
        acc.z += xv.x * w0.z + xv.y * w1.z + xv.z * w2.z + xv.w * w3.z;
        acc.w += xv.x * w0.w + xv.y * w1.w + xv.z * w2.w + xv.w * w3.w;
    }
    *reinterpret_cast<float4*>(&Y[(size_t)row * HD + col]) = acc;
}

// ---------------- SpMM gather: one wave per dst node, lane = feature ----------------
// out_type t accumulates relations 2t (src x0-side) and 2t+1 (src x1-side).

__global__ void spmm_kernel(const float* __restrict__ Ybase, const int* __restrict__ rowptr,
                            const int* __restrict__ ssrc, const float* __restrict__ sw,
                            float* __restrict__ act, float* __restrict__ outp,
                            int N, int E, int relu) {
    int t = blockIdx.y;
    int wave = threadIdx.x >> 6;
    int lane = threadIdx.x & 63;
    int d = blockIdx.x * 4 + wave;
    if (d >= N) return;
    float acc = 0.f;
    #pragma unroll
    for (int rr = 0; rr < 2; ++rr) {
        int r = 2 * t + rr;
        const float* Y = Ybase + (size_t)r * N * HD;
        const int* sp = ssrc + (size_t)r * E;
        const float* wp = sw + (size_t)r * E;
        int beg = rowptr[(size_t)r * (N + 1) + d];
        int end = rowptr[(size_t)r * (N + 1) + d + 1];
        int e = beg;
        int s0 = 0; float w0 = 0.f;
        if (e < end) { s0 = sp[e]; w0 = wp[e]; }
        for (; e < end; ++e) {
            int s1 = 0; float w1 = 0.f;
            if (e + 1 < end) { s1 = sp[e + 1]; w1 = wp[e + 1]; }
            acc += w0 * Y[(size_t)s0 * HD + lane];
            s0 = s1; w0 = w1;
        }
    }
    if (relu) acc = fmaxf(acc, 0.f);
    if (act) act[((size_t)t * N + d) * HD + lane] = acc;
    if (outp) outp[((size_t)t * N + d) * 192 + lane] = acc;
}

// ---------------- orchestration ----------------

extern "C" void kernel_launch(void* const* d_in, const int* in_sizes, int n_in,
                              void* d_out, int out_size, void* d_ws, size_t ws_size,
                              hipStream_t stream) {
    const float* x0 = (const float*)d_in[0];
    const float* x1 = (const float*)d_in[1];
    const int* src = (const int*)d_in[2];
    const int* dst = (const int*)d_in[3];
    const float* ew = (const float*)d_in[4];
    const float* W1 = (const float*)d_in[5];
    const float* Wl = (const float*)d_in[6];
    float* out = (float*)d_out;

    int N = in_sizes[0] / FD;
    int E = in_sizes[2] / NREL;

    char* ws = (char*)d_ws;
    size_t off = 0;
    auto alloc = [&](size_t bytes) -> void* {
        void* p = ws + off;
        off = (off + bytes + 255) & ~(size_t)255;
        return p;
    };
    int* deg     = (int*)alloc((size_t)NREL * N * 4);
    int* rowptr  = (int*)alloc((size_t)NREL * (N + 1) * 4);
    int* cursor  = (int*)alloc((size_t)NREL * N * 4);
    int* ssrc    = (int*)alloc((size_t)NREL * E * 4);
    float* sw    = (float*)alloc((size_t)NREL * E * 4);
    float* y     = (float*)alloc((size_t)NREL * N * HD * 4);
    float* act   = (float*)alloc((size_t)2 * N * HD * 4);
    (void)ws_size;

    // CSR build (src/dst/ew are constant, but we must recompute every call)
    hipMemsetAsync(deg, 0, (size_t)NREL * N * 4, stream);
    int eblocks = idiv_up(E, 256); if (eblocks > 2048) eblocks = 2048;
    dim3 egrid(eblocks, NREL);
    hist_kernel<<<egrid, 256, 0, stream>>>(dst, deg, E, N);
    scan_kernel<<<NREL, 1024, 0, stream>>>(deg, rowptr, cursor, N, E);
    fill_kernel<<<egrid, 256, 0, stream>>>(src, dst, ew, cursor, ssrc, sw, E, N);

    dim3 ggrid(idiv_up(N, 16), NREL);
    dim3 sgrid(idiv_up(N, 4), 2);

    // layer 1: h1 = relu(spmm(x @ W1)); store act + out[:, :, 0:64]
    gemm_kernel<FD><<<ggrid, 256, 0, stream>>>(x0, x1, W1, y, N);
    spmm_kernel<<<sgrid, 256, 0, stream>>>(y, rowptr, ssrc, sw, act, out + 0, N, E, 1);

    // layers 2..5 with Wl[0..3]
    for (int l = 0; l < 4; ++l) {
        gemm_kernel<HD><<<ggrid, 256, 0, stream>>>(act, act + (size_t)N * HD,
                                                   Wl + (size_t)l * NREL * HD * HD, y, N);
        float* op = (l == 0) ? (out + 64) : (l == 3) ? (out + 128) : nullptr;
        float* ap = (l == 3) ? nullptr : act;
        int relu = (l == 3) ? 0 : 1;
        spmm_kernel<<<sgrid, 256, 0, stream>>>(y, rowptr, ssrc, sw, ap, op, N, E, relu);
    }
}

// Round 2
// 1305.515 us; speedup vs baseline: 1.5915x; 1.5915x over previous
//
#include <hip/hip_runtime.h>
#include <cstddef>

#define NREL 4
#define HD 64
#define FD 128

static inline int idiv_up(int a, int b) { return (a + b - 1) / b; }

// ---------------- CSR build (dst-sorted adjacency, per relation) ----------------

__global__ void hist_kernel(const int* __restrict__ dst, int* __restrict__ deg, int E, int N) {
    int k = blockIdx.y;
    const int* dk = dst + (size_t)k * E;
    int* degk = deg + (size_t)k * N;
    for (int e = blockIdx.x * blockDim.x + threadIdx.x; e < E; e += gridDim.x * blockDim.x)
        atomicAdd(&degk[dk[e]], 1);
}

// one block (1024 threads) per relation: chunked exclusive scan via wave shuffles
__global__ void scan_kernel(const int* __restrict__ deg, int* __restrict__ rowptr,
                            int* __restrict__ cursor, int N, int E) {
    int k = blockIdx.x;
    __shared__ int wsum[16];
    __shared__ int scarry;
    int tid = threadIdx.x;
    int wid = tid >> 6, lane = tid & 63;
    if (tid == 0) scarry = 0;
    __syncthreads();
    for (int base = 0; base < N; base += 1024) {
        int i = base + tid;
        int v = (i < N) ? deg[(size_t)k * N + i] : 0;
        // wave-inclusive scan
        int x = v;
        #pragma unroll
        for (int off = 1; off < 64; off <<= 1) {
            int y = __shfl_up(x, off, 64);
            if (lane >= off) x += y;
        }
        if (lane == 63) wsum[wid] = x;
        __syncthreads();
        if (wid == 0) {
            int s = (lane < 16) ? wsum[lane] : 0;
            #pragma unroll
            for (int off = 1; off < 16; off <<= 1) {
                int y = __shfl_up(s, off, 64);
                if (lane >= off) s += y;
            }
            if (lane < 16) wsum[lane] = s;
        }
        __syncthreads();
        int waveoff = wid ? wsum[wid - 1] : 0;
        int incl = x + waveoff;
        int carry = scarry;
        if (i < N) {
            int excl = carry + incl - v;
            rowptr[(size_t)k * (N + 1) + i] = excl;
            cursor[(size_t)k * N + i] = excl;
        }
        __syncthreads();
        if (tid == 1023) scarry = carry + incl;
        __syncthreads();
    }
    if (tid == 0) rowptr[(size_t)k * (N + 1) + N] = E;
}

__global__ void fill_kernel(const int* __restrict__ src, const int* __restrict__ dst,
                            const float* __restrict__ ew, int* __restrict__ cursor,
                            int2* __restrict__ edges, int E, int N) {
    int k = blockIdx.y;
    const int* sk = src + (size_t)k * E;
    const int* dk = dst + (size_t)k * E;
    const float* wk = ew + (size_t)k * E;
    int* ck = cursor + (size_t)k * N;
    int2* ek = edges + (size_t)k * E;
    for (int e = blockIdx.x * blockDim.x + threadIdx.x; e < E; e += gridDim.x * blockDim.x) {
        int d = dk[e];
        int pos = atomicAdd(&ck[d], 1);
        ek[pos] = make_int2(sk[e], __float_as_int(wk[e]));
    }
}

// ---------------- Dense GEMM: Y[k] = X_{k%2} @ W_k  (K x 64), W in LDS ----------------

template <int K>
__global__ void gemm_kernel(const float* __restrict__ X0, const float* __restrict__ X1,
                            const float* __restrict__ Wbase, float* __restrict__ Ybase, int N) {
    __shared__ float sW[K * HD];
    int k = blockIdx.y;
    const float* X = (k & 1) ? X1 : X0;
    const float* W = Wbase + (size_t)k * K * HD;
    float* Y = Ybase + (size_t)k * N * HD;
    int tid = threadIdx.x;
    for (int i = tid * 4; i < K * HD; i += 256 * 4)
        *reinterpret_cast<float4*>(&sW[i]) = *reinterpret_cast<const float4*>(&W[i]);
    __syncthreads();
    int row = blockIdx.x * 16 + (tid >> 4);
    int col = (tid & 15) * 4;
    if (row >= N) return;
    const float* xr = X + (size_t)row * K;
    float4 acc = {0.f, 0.f, 0.f, 0.f};
    #pragma unroll 8
    for (int kk = 0; kk < K; kk += 4) {
        float4 xv = *reinterpret_cast<const float4*>(xr + kk);
        float4 w0 = *reinterpret_cast<const float4*>(&sW[(kk + 0) * HD + col]);
        float4 w1 = *reinterpret_cast<const float4*>(&sW[(kk + 1) * HD + col]);
        float4 w2 = *reinterpret_cast<const float4*>(&sW[(kk + 2) * HD + col]);
        float4 w3 = *reinterpret_cast<const float4*>(&sW[(kk + 3) * HD + col]);
        acc.x += xv.x * w0.x + xv.y * w1.x + xv.z * w2.x + xv.w * w3.x;
        acc.y += xv.x * w0.y + xv.y * w1.y + xv.z * w2.y + xv.w * w3.y;
        acc.z += xv.x * w0.z + xv.y * w1.z + xv.z * w2.z + xv.w * w3.z;
        acc.w += xv.x * w0.w + xv.y * w1.w + xv.z * w2.w + xv.w * w3.w;
    }
    *reinterpret_cast<float4*>(&Y[(size_t)row * HD + col]) = acc;
}

// ---------------- SpMM gather: one wave per dst node, lane = feature ----------------
// out_type t accumulates relations 2t (src x0-side) and 2t+1 (src x1-side).
// 4-deep unrolled: 4 independent gathers in flight per wave.

__global__ void spmm_kernel(const float* __restrict__ Ybase, const int* __restrict__ rowptr,
                            const int2* __restrict__ edges,
                            float* __restrict__ act, float* __restrict__ outp,
                            int N, int E, int relu) {
    int t = blockIdx.y;
    int wave = threadIdx.x >> 6;
    int lane = threadIdx.x & 63;
    int d = blockIdx.x * 4 + wave;
    if (d >= N) return;
    float a0 = 0.f, a1 = 0.f, a2 = 0.f, a3 = 0.f;
    #pragma unroll
    for (int rr = 0; rr < 2; ++rr) {
        int r = 2 * t + rr;
        const float* Y = Ybase + (size_t)r * N * HD;
        const int2* ep = edges + (size_t)r * E;
        int e = rowptr[(size_t)r * (N + 1) + d];
        int end = rowptr[(size_t)r * (N + 1) + d + 1];
        for (; e + 4 <= end; e += 4) {
            int2 e0 = ep[e + 0];
            int2 e1 = ep[e + 1];
            int2 e2 = ep[e + 2];
            int2 e3 = ep[e + 3];
            float y0 = Y[(size_t)e0.x * HD + lane];
            float y1 = Y[(size_t)e1.x * HD + lane];
            float y2 = Y[(size_t)e2.x * HD + lane];
            float y3 = Y[(size_t)e3.x * HD + lane];
            a0 += __int_as_float(e0.y) * y0;
            a1 += __int_as_float(e1.y) * y1;
            a2 += __int_as_float(e2.y) * y2;
            a3 += __int_as_float(e3.y) * y3;
        }
        for (; e < end; ++e) {
            int2 ee = ep[e];
            a0 += __int_as_float(ee.y) * Y[(size_t)ee.x * HD + lane];
        }
    }
    float acc = (a0 + a1) + (a2 + a3);
    if (relu) acc = fmaxf(acc, 0.f);
    if (act) act[((size_t)t * N + d) * HD + lane] = acc;
    if (outp) outp[((size_t)t * N + d) * 192 + lane] = acc;
}

// ---------------- orchestration ----------------

extern "C" void kernel_launch(void* const* d_in, const int* in_sizes, int n_in,
                              void* d_out, int out_size, void* d_ws, size_t ws_size,
                              hipStream_t stream) {
    const float* x0 = (const float*)d_in[0];
    const float* x1 = (const float*)d_in[1];
    const int* src = (const int*)d_in[2];
    const int* dst = (const int*)d_in[3];
    const float* ew = (const float*)d_in[4];
    const float* W1 = (const float*)d_in[5];
    const float* Wl = (const float*)d_in[6];
    float* out = (float*)d_out;

    int N = in_sizes[0] / FD;
    int E = in_sizes[2] / NREL;

    char* ws = (char*)d_ws;
    size_t off = 0;
    auto alloc = [&](size_t bytes) -> void* {
        void* p = ws + off;
        off = (off + bytes + 255) & ~(size_t)255;
        return p;
    };
    int* deg     = (int*)alloc((size_t)NREL * N * 4);
    int* rowptr  = (int*)alloc((size_t)NREL * (N + 1) * 4);
    int* cursor  = (int*)alloc((size_t)NREL * N * 4);
    int2* edges  = (int2*)alloc((size_t)NREL * E * 8);
    float* y     = (float*)alloc((size_t)NREL * N * HD * 4);
    float* act   = (float*)alloc((size_t)2 * N * HD * 4);
    (void)ws_size;

    // CSR build (src/dst/ew are constant, but we must recompute every call)
    hipMemsetAsync(deg, 0, (size_t)NREL * N * 4, stream);
    int eblocks = idiv_up(E, 256); if (eblocks > 2048) eblocks = 2048;
    dim3 egrid(eblocks, NREL);
    hist_kernel<<<egrid, 256, 0, stream>>>(dst, deg, E, N);
    scan_kernel<<<NREL, 1024, 0, stream>>>(deg, rowptr, cursor, N, E);
    fill_kernel<<<egrid, 256, 0, stream>>>(src, dst, ew, cursor, edges, E, N);

    dim3 ggrid(idiv_up(N, 16), NREL);
    dim3 sgrid(idiv_up(N, 4), 2);

    // layer 1: h1 = relu(spmm(x @ W1)); store act + out[:, :, 0:64]
    gemm_kernel<FD><<<ggrid, 256, 0, stream>>>(x0, x1, W1, y, N);
    spmm_kernel<<<sgrid, 256, 0, stream>>>(y, rowptr, edges, act, out + 0, N, E, 1);

    // layers 2..5 with Wl[0..3]
    for (int l = 0; l < 4; ++l) {
        gemm_kernel<HD><<<ggrid, 256, 0, stream>>>(act, act + (size_t)N * HD,
                                                   Wl + (size_t)l * NREL * HD * HD, y, N);
        float* op = (l == 0) ? (out + 64) : (l == 3) ? (out + 128) : nullptr;
        float* ap = (l == 3) ? nullptr : act;
        int relu = (l == 3) ? 0 : 1;
        spmm_kernel<<<sgrid, 256, 0, stream>>>(y, rowptr, edges, ap, op, N, E, relu);
    }
}